// Round 8
// baseline (163.787 us; speedup 1.0000x reference)
//
#include <hip/hip_runtime.h>
#include <cmath>

namespace {

constexpr int N = 32, T = 1024, C = 512, K = 64;
constexpr float EPS = 1e-12f;

typedef short s8v __attribute__((ext_vector_type(8)));   // 8 x bf16 bits
typedef short s4v __attribute__((ext_vector_type(4)));   // 4 x bf16 bits
typedef float f4v __attribute__((ext_vector_type(4)));   // MFMA accumulator

__device__ inline unsigned short f2bh(float f) {
  __bf16 h = (__bf16)f;
  return __builtin_bit_cast(unsigned short, h);
}
__device__ inline float bh2f(unsigned short u) {
  __bf16 h = __builtin_bit_cast(__bf16, u);
  return (float)h;
}

#define MFMA16(A, B, Cc) __builtin_amdgcn_mfma_f32_16x16x32_bf16((A), (B), (Cc), 0, 0, 0)

// ---------------------------------------------------------------------------
// k_gemm1: logits = x @ W^T + b (split-bf16 3-pass MFMA), softmax over K,
// writes a^T [n][k][t] as hi/lo bf16 + asum_part[block][64].
// Also zero-inits ssq + counter for k_gemm2 (block 0).
// Grid NT/64 = 512 x 256 threads (4 waves; wave = 32t x 32k, 2x2 micro).
// ---------------------------------------------------------------------------
__global__ __launch_bounds__(256, 4) void k_gemm1(
    const float* __restrict__ x, const float* __restrict__ W,
    const float* __restrict__ b, unsigned short* __restrict__ ath,
    unsigned short* __restrict__ atl, float* __restrict__ asum_part,
    float* __restrict__ ssq, unsigned int* __restrict__ counter) {
  __shared__ __align__(16) unsigned short sm[4 * 64 * 72];  // 36864 B
  __shared__ float asum_l[256];
  unsigned short* xh_s = sm;                // [64 t][72] bf16
  unsigned short* xl_s = sm + 64 * 72;
  unsigned short* wh_s = sm + 2 * 64 * 72;  // [64 k][72]
  unsigned short* wl_s = sm + 3 * 64 * 72;

  const int tid = threadIdx.x;
  const int w = tid >> 6, lane = tid & 63, lm = lane & 15, lq = lane >> 4;
  const int th = w >> 1;  // t-half (32 rows)
  const int kh = w & 1;   // k-half (32 cols)
  const long r0 = (long)blockIdx.x * 64;
  const int n = blockIdx.x >> 4, tl = blockIdx.x & 15;

  if (blockIdx.x == 0) {  // init sync state for k_gemm2 (kernel-boundary order)
    if (tid < 32) counter[tid] = 0u;
#pragma unroll
    for (int q = 0; q < 8; ++q) ssq[tid * 8 + q] = 0.f;
  }

  f4v acc[2][2] = {};
  float4 px[4], pw[4];
#pragma unroll
  for (int r = 0; r < 4; ++r) {
    const int f = tid + r * 256, t = f >> 4, cg = f & 15;
    px[r] = *(const float4*)&x[(r0 + t) * C + cg * 4];
    pw[r] = *(const float4*)&W[(long)t * C + cg * 4];
  }

  for (int c0 = 0; c0 < C; c0 += 64) {
    __syncthreads();
#pragma unroll
    for (int r = 0; r < 4; ++r) {
      const int f = tid + r * 256, t = f >> 4, cg = f & 15;
      const float ex[4] = {px[r].x, px[r].y, px[r].z, px[r].w};
      const float ew[4] = {pw[r].x, pw[r].y, pw[r].z, pw[r].w};
      s4v xh, xl, wh, wl;
#pragma unroll
      for (int i = 0; i < 4; ++i) {
        unsigned short hb = f2bh(ex[i]);
        xh[i] = (short)hb; xl[i] = (short)f2bh(ex[i] - bh2f(hb));
        hb = f2bh(ew[i]);
        wh[i] = (short)hb; wl[i] = (short)f2bh(ew[i] - bh2f(hb));
      }
      *(s4v*)&xh_s[t * 72 + cg * 4] = xh;
      *(s4v*)&xl_s[t * 72 + cg * 4] = xl;
      *(s4v*)&wh_s[t * 72 + cg * 4] = wh;
      *(s4v*)&wl_s[t * 72 + cg * 4] = wl;
    }
    if (c0 + 64 < C) {  // prefetch next chunk
#pragma unroll
      for (int r = 0; r < 4; ++r) {
        const int f = tid + r * 256, t = f >> 4, cg = f & 15;
        px[r] = *(const float4*)&x[(r0 + t) * C + c0 + 64 + cg * 4];
        pw[r] = *(const float4*)&W[(long)t * C + c0 + 64 + cg * 4];
      }
    }
    __syncthreads();

#pragma unroll
    for (int ks = 0; ks < 2; ++ks) {
      const int col = ks * 32 + lq * 8;
      s8v ah[2], al[2], bh[2], bl[2];
#pragma unroll
      for (int i = 0; i < 2; ++i) {
        ah[i] = *(const s8v*)&xh_s[(th * 32 + i * 16 + lm) * 72 + col];
        al[i] = *(const s8v*)&xl_s[(th * 32 + i * 16 + lm) * 72 + col];
        bh[i] = *(const s8v*)&wh_s[(kh * 32 + i * 16 + lm) * 72 + col];
        bl[i] = *(const s8v*)&wl_s[(kh * 32 + i * 16 + lm) * 72 + col];
      }
#pragma unroll
      for (int i = 0; i < 2; ++i)
#pragma unroll
        for (int j = 0; j < 2; ++j) {
          acc[i][j] = MFMA16(ah[i], bh[j], acc[i][j]);
          acc[i][j] = MFMA16(ah[i], bl[j], acc[i][j]);
          acc[i][j] = MFMA16(al[i], bh[j], acc[i][j]);
        }
    }
  }
  __syncthreads();

  // logits + bias -> LDS Ls[64 t][68] fp32 ; Ls2 = a^T staging [64 k][68]
  float* Ls = (float*)sm;            // 17408 B
  float* Ls2 = (float*)(sm + 8704);  // 17408 B
  const float bias[2] = {b[kh * 32 + lm], b[kh * 32 + 16 + lm]};
#pragma unroll
  for (int i = 0; i < 2; ++i)
#pragma unroll
    for (int j = 0; j < 2; ++j)
#pragma unroll
      for (int r = 0; r < 4; ++r)
        Ls[(th * 32 + i * 16 + lq * 4 + r) * 68 + kh * 32 + j * 16 + lm] =
            acc[i][j][r] + bias[j];
  __syncthreads();

  // softmax: 4 threads per t-row, 16 k each, register + shfl
  {
    const int row = tid >> 2, q = tid & 3;
    float av[16];
#pragma unroll
    for (int u = 0; u < 4; ++u)
      *(float4*)&av[u * 4] = *(const float4*)&Ls[row * 68 + q * 16 + u * 4];
    float m = av[0];
#pragma unroll
    for (int i = 1; i < 16; ++i) m = fmaxf(m, av[i]);
    m = fmaxf(m, __shfl_xor(m, 1, 64));
    m = fmaxf(m, __shfl_xor(m, 2, 64));
    float sum = 0.f;
#pragma unroll
    for (int i = 0; i < 16; ++i) {
      av[i] = __expf(av[i] - m);
      sum += av[i];
    }
    sum += __shfl_xor(sum, 1, 64);
    sum += __shfl_xor(sum, 2, 64);
    const float inv = 1.f / sum;
    float ps[16];
#pragma unroll
    for (int i = 0; i < 16; ++i) {
      av[i] *= inv;
      ps[i] = av[i];
      Ls2[(q * 16 + i) * 68 + row] = av[i];  // transposed a^T [k][t]
    }
#pragma unroll
    for (int s = 4; s < 64; s <<= 1)
#pragma unroll
      for (int i = 0; i < 16; ++i) ps[i] += __shfl_xor(ps[i], s, 64);
    if (lane < 4) {
#pragma unroll
      for (int i = 0; i < 16; ++i) asum_l[w * 64 + q * 16 + i] = ps[i];
    }
  }
  __syncthreads();

  if (tid < 64) {
    asum_part[(n * 16 + tl) * 64 + tid] = asum_l[tid] + asum_l[64 + tid] +
                                          asum_l[128 + tid] + asum_l[192 + tid];
  }
  // a^T global write [n][k][t] as hi/lo bf16 (convert from LDS fp32)
#pragma unroll
  for (int r = 0; r < 4; ++r) {
    const int u = tid + r * 256, k = u >> 4, tg = u & 15;
    const float4 v = *(const float4*)&Ls2[k * 68 + tg * 4];
    const float e[4] = {v.x, v.y, v.z, v.w};
    s4v h, l;
#pragma unroll
    for (int i = 0; i < 4; ++i) {
      unsigned short hb = f2bh(e[i]);
      h[i] = (short)hb;
      l[i] = (short)f2bh(e[i] - bh2f(hb));
    }
    *(s4v*)&ath[((long)n * K + k) * T + tl * 64 + tg * 4] = h;
    *(s4v*)&atl[((long)n * K + k) * T + tl * 64 + tg * 4] = l;
  }
}

// ---------------------------------------------------------------------------
// k_gemm2: fully fused second half. vlad = aT @ x - asum*cent stays in
// registers; ssq via device atomics; per-n counter spin (8 sibling blocks,
// all 256 blocks co-resident at 1 block/CU); normalize and write out.
// Grid N*8 = 256 blocks (n, 64c) x 256 threads (4 waves; wave = 32k x 32c).
// ---------------------------------------------------------------------------
__global__ __launch_bounds__(256, 2) void k_gemm2(
    const float* __restrict__ x, const unsigned short* __restrict__ ath,
    const unsigned short* __restrict__ atl,
    const float* __restrict__ asum_part, const float* __restrict__ cent,
    float* __restrict__ ssq, unsigned int* __restrict__ counter,
    float* __restrict__ out) {
  __shared__ __align__(16) unsigned short sm[4 * 64 * 72];  // 36864 B
  __shared__ float asum_l[64];
  __shared__ float ssq_l[128];
  __shared__ float denom_l[64];
  __shared__ float contrib_l[64];
  __shared__ float ginv_s;
  unsigned short* ah_s = sm;                // a^T hi [64 k][72]
  unsigned short* al_s = sm + 64 * 72;
  unsigned short* xh_s = sm + 2 * 64 * 72;  // x^T hi [64 c][72]
  unsigned short* xl_s = sm + 3 * 64 * 72;

  const int tid = threadIdx.x;
  const int w = tid >> 6, lane = tid & 63, lm = lane & 15, lq = lane >> 4;
  const int kh = w >> 1;  // 32k half
  const int ch = w & 1;   // 32c half
  const int n = blockIdx.x >> 3, cb = blockIdx.x & 7;
  const int c0 = cb * 64;

  if (tid < 64) {
    float s = 0.f;
#pragma unroll
    for (int tl = 0; tl < 16; ++tl) s += asum_part[(n * 16 + tl) * 64 + tid];
    asum_l[tid] = s;
  }

  f4v acc[2][2] = {};
  s8v pah[2], pal[2];
  float4 px[4];
  // preload tile 0
#pragma unroll
  for (int r = 0; r < 2; ++r) {
    const int u = tid + r * 256, k = u >> 3, tg = u & 7;
    pah[r] = *(const s8v*)&ath[((long)n * K + k) * T + tg * 8];
    pal[r] = *(const s8v*)&atl[((long)n * K + k) * T + tg * 8];
  }
  {
    const int cg = tid & 15, tq = tid >> 4;
#pragma unroll
    for (int i = 0; i < 4; ++i)
      px[i] = *(const float4*)&x[((long)n * T + tq * 4 + i) * C + c0 + cg * 4];
  }

  for (int t0 = 0; t0 < T; t0 += 64) {
    __syncthreads();
    // a^T: pure b128 copy (already hi/lo bf16)
#pragma unroll
    for (int r = 0; r < 2; ++r) {
      const int u = tid + r * 256, k = u >> 3, tg = u & 7;
      *(s8v*)&ah_s[k * 72 + tg * 8] = pah[r];
      *(s8v*)&al_s[k * 72 + tg * 8] = pal[r];
    }
    // x^T: fp32 -> hi/lo, 4-t packed transposed writes
    {
      const int cg = tid & 15, tq = tid >> 4, t4 = tq * 4;
#pragma unroll
      for (int cc = 0; cc < 4; ++cc) {
        s4v h, l;
#pragma unroll
        for (int i = 0; i < 4; ++i) {
          const float e = ((const float*)&px[i])[cc];
          unsigned short hb = f2bh(e);
          h[i] = (short)hb;
          l[i] = (short)f2bh(e - bh2f(hb));
        }
        *(s4v*)&xh_s[(cg * 4 + cc) * 72 + t4] = h;
        *(s4v*)&xl_s[(cg * 4 + cc) * 72 + t4] = l;
      }
    }
    if (t0 + 64 < T) {  // prefetch next t-tile
#pragma unroll
      for (int r = 0; r < 2; ++r) {
        const int u = tid + r * 256, k = u >> 3, tg = u & 7;
        pah[r] = *(const s8v*)&ath[((long)n * K + k) * T + t0 + 64 + tg * 8];
        pal[r] = *(const s8v*)&atl[((long)n * K + k) * T + t0 + 64 + tg * 8];
      }
      const int cg = tid & 15, tq = tid >> 4;
#pragma unroll
      for (int i = 0; i < 4; ++i)
        px[i] = *(const float4*)&x[((long)n * T + t0 + 64 + tq * 4 + i) * C +
                                   c0 + cg * 4];
    }
    __syncthreads();

#pragma unroll
    for (int ks = 0; ks < 2; ++ks) {
      const int col = ks * 32 + lq * 8;
      s8v ah[2], al[2], bh[2], bl[2];
#pragma unroll
      for (int i = 0; i < 2; ++i) {
        ah[i] = *(const s8v*)&ah_s[(kh * 32 + i * 16 + lm) * 72 + col];
        al[i] = *(const s8v*)&al_s[(kh * 32 + i * 16 + lm) * 72 + col];
        bh[i] = *(const s8v*)&xh_s[(ch * 32 + i * 16 + lm) * 72 + col];
        bl[i] = *(const s8v*)&xl_s[(ch * 32 + i * 16 + lm) * 72 + col];
      }
#pragma unroll
      for (int i = 0; i < 2; ++i)
#pragma unroll
        for (int j = 0; j < 2; ++j) {
          acc[i][j] = MFMA16(ah[i], bh[j], acc[i][j]);
          acc[i][j] = MFMA16(ah[i], bl[j], acc[i][j]);
          acc[i][j] = MFMA16(al[i], bh[j], acc[i][j]);
        }
    }
  }

  // epilogue: v = acc - asum*cent (in registers), ssq partial -> atomics
  float ssqp[2][4];
#pragma unroll
  for (int i = 0; i < 2; ++i)
#pragma unroll
    for (int r = 0; r < 4; ++r) ssqp[i][r] = 0.f;

#pragma unroll
  for (int i = 0; i < 2; ++i) {
#pragma unroll
    for (int r = 0; r < 4; ++r) {
      const int k = kh * 32 + i * 16 + lq * 4 + r;
      const float as = asum_l[k];
#pragma unroll
      for (int j = 0; j < 2; ++j) {
        const int c = c0 + ch * 32 + j * 16 + lm;
        const float v = acc[i][j][r] - as * cent[(long)k * C + c];
        acc[i][j][r] = v;  // keep for the final scaled write
        ssqp[i][r] += v * v;
      }
    }
  }
#pragma unroll
  for (int i = 0; i < 2; ++i)
#pragma unroll
    for (int r = 0; r < 4; ++r) {
      float s = ssqp[i][r];
      s += __shfl_xor(s, 1, 64);
      s += __shfl_xor(s, 2, 64);
      s += __shfl_xor(s, 4, 64);
      s += __shfl_xor(s, 8, 64);
      ssqp[i][r] = s;
    }
  if (lm == 0) {
#pragma unroll
    for (int i = 0; i < 2; ++i)
#pragma unroll
      for (int r = 0; r < 4; ++r)
        ssq_l[(kh * 32 + i * 16 + lq * 4 + r) * 2 + ch] = ssqp[i][r];
  }
  __syncthreads();
  if (tid < 64) atomicAdd(&ssq[n * K + tid], ssq_l[tid * 2] + ssq_l[tid * 2 + 1]);
  __threadfence();   // drain ssq atomics to the coherent point
  __syncthreads();

  // inter-block sync: 8 sibling blocks per n (all blocks co-resident)
  if (tid == 0) {
    atomicAdd(&counter[n], 1u);
    while (__hip_atomic_load(&counter[n], __ATOMIC_RELAXED,
                             __HIP_MEMORY_SCOPE_AGENT) < 8u)
      __builtin_amdgcn_s_sleep(8);
  }
  __syncthreads();
  __threadfence();   // acquire: invalidate caches before reading ssq

  if (tid < 64) {
    const float sv = __hip_atomic_load(&ssq[n * K + tid], __ATOMIC_RELAXED,
                                       __HIP_MEMORY_SCOPE_AGENT);
    const float d = fmaxf(sqrtf(sv), EPS);
    denom_l[tid] = d;
    contrib_l[tid] = sv / (d * d);
  }
  __syncthreads();
  if (tid == 0) {
    float s = 0.f;
#pragma unroll
    for (int k = 0; k < K; ++k) s += contrib_l[k];
    ginv_s = 1.0f / fmaxf(sqrtf(s), EPS);
  }
  __syncthreads();

  const float gi = ginv_s;
#pragma unroll
  for (int i = 0; i < 2; ++i)
#pragma unroll
    for (int r = 0; r < 4; ++r) {
      const int k = kh * 32 + i * 16 + lq * 4 + r;
      const float sc = gi / denom_l[k];
#pragma unroll
      for (int j = 0; j < 2; ++j) {
        const int c = c0 + ch * 32 + j * 16 + lm;
        out[((long)n * K + k) * C + c] = acc[i][j][r] * sc;
      }
    }
}

}  // namespace

extern "C" void kernel_launch(void* const* d_in, const int* in_sizes, int n_in,
                              void* d_out, int out_size, void* d_ws,
                              size_t ws_size, hipStream_t stream) {
  const float* x = reinterpret_cast<const float*>(d_in[0]);     // [N,T,C]
  const float* W = reinterpret_cast<const float*>(d_in[1]);     // [K,C]
  const float* b = reinterpret_cast<const float*>(d_in[2]);     // [K]
  const float* cent = reinterpret_cast<const float*>(d_in[3]);  // [K,C]
  float* out = reinterpret_cast<float*>(d_out);                 // [N, K*C]

  char* p = (char*)d_ws;
  unsigned short* ath = (unsigned short*)p;  p += (size_t)N * K * T * 2;  // 4 MiB
  unsigned short* atl = (unsigned short*)p;  p += (size_t)N * K * T * 2;  // 4 MiB
  float* asum_part = (float*)p;              p += (size_t)512 * 64 * 4;   // 128 KiB
  float* ssq = (float*)p;                    p += (size_t)N * K * 4;      // 8 KiB
  unsigned int* counter = (unsigned int*)p;                               // 128 B

  k_gemm1<<<(N * T) / 64, 256, 0, stream>>>(x, W, b, ath, atl, asum_part, ssq,
                                            counter);
  k_gemm2<<<N * 8, 256, 0, stream>>>(x, ath, atl, asum_part, cent, ssq, counter,
                                     out);
}

// Round 9
// 127.286 us; speedup vs baseline: 1.2868x; 1.2868x over previous
//
#include <hip/hip_runtime.h>
#include <cmath>

namespace {

constexpr int N = 32, T = 1024, C = 512, K = 64;
constexpr float EPS = 1e-12f;

typedef short s8v __attribute__((ext_vector_type(8)));   // 8 x bf16 bits
typedef short s4v __attribute__((ext_vector_type(4)));   // 4 x bf16 bits
typedef short s2v __attribute__((ext_vector_type(2)));   // 2 x bf16 bits
typedef float f4v __attribute__((ext_vector_type(4)));   // MFMA accumulator

__device__ inline unsigned short f2bh(float f) {
  __bf16 h = (__bf16)f;
  return __builtin_bit_cast(unsigned short, h);
}
__device__ inline float bh2f(unsigned short u) {
  __bf16 h = __builtin_bit_cast(__bf16, u);
  return (float)h;
}

#define MFMA16(A, B, Cc) __builtin_amdgcn_mfma_f32_16x16x32_bf16((A), (B), (Cc), 0, 0, 0)

// ---------------------------------------------------------------------------
// k_gemm1: logits = x @ W^T + b (split-bf16 3-pass MFMA), softmax over K,
// writes a^T [n][k][t] fp32 + asum_part[block][64].  (round-5 proven)
// Grid NT/64 = 512 x 256 threads (4 waves; wave = 32t x 32k, 2x2 micro).
// ---------------------------------------------------------------------------
__global__ __launch_bounds__(256, 4) void k_gemm1(
    const float* __restrict__ x, const float* __restrict__ W,
    const float* __restrict__ b, float* __restrict__ aT,
    float* __restrict__ asum_part) {
  __shared__ __align__(16) unsigned short sm[4 * 64 * 72];  // 36864 B
  __shared__ float asum_l[256];
  unsigned short* xh_s = sm;                // [64 t][72] bf16
  unsigned short* xl_s = sm + 64 * 72;
  unsigned short* wh_s = sm + 2 * 64 * 72;  // [64 k][72]
  unsigned short* wl_s = sm + 3 * 64 * 72;

  const int tid = threadIdx.x;
  const int w = tid >> 6, lane = tid & 63, lm = lane & 15, lq = lane >> 4;
  const int th = w >> 1;  // t-half (32 rows)
  const int kh = w & 1;   // k-half (32 cols)
  const long r0 = (long)blockIdx.x * 64;
  const int n = blockIdx.x >> 4, tl = blockIdx.x & 15;

  f4v acc[2][2] = {};
  float4 px[4], pw[4];
#pragma unroll
  for (int r = 0; r < 4; ++r) {
    const int f = tid + r * 256, t = f >> 4, cg = f & 15;
    px[r] = *(const float4*)&x[(r0 + t) * C + cg * 4];
    pw[r] = *(const float4*)&W[(long)t * C + cg * 4];
  }

  for (int c0 = 0; c0 < C; c0 += 64) {
    __syncthreads();
#pragma unroll
    for (int r = 0; r < 4; ++r) {
      const int f = tid + r * 256, t = f >> 4, cg = f & 15;
      const float ex[4] = {px[r].x, px[r].y, px[r].z, px[r].w};
      const float ew[4] = {pw[r].x, pw[r].y, pw[r].z, pw[r].w};
      s4v xh, xl, wh, wl;
#pragma unroll
      for (int i = 0; i < 4; ++i) {
        unsigned short hb = f2bh(ex[i]);
        xh[i] = (short)hb; xl[i] = (short)f2bh(ex[i] - bh2f(hb));
        hb = f2bh(ew[i]);
        wh[i] = (short)hb; wl[i] = (short)f2bh(ew[i] - bh2f(hb));
      }
      *(s4v*)&xh_s[t * 72 + cg * 4] = xh;
      *(s4v*)&xl_s[t * 72 + cg * 4] = xl;
      *(s4v*)&wh_s[t * 72 + cg * 4] = wh;
      *(s4v*)&wl_s[t * 72 + cg * 4] = wl;
    }
    if (c0 + 64 < C) {  // prefetch next chunk
#pragma unroll
      for (int r = 0; r < 4; ++r) {
        const int f = tid + r * 256, t = f >> 4, cg = f & 15;
        px[r] = *(const float4*)&x[(r0 + t) * C + c0 + 64 + cg * 4];
        pw[r] = *(const float4*)&W[(long)t * C + c0 + 64 + cg * 4];
      }
    }
    __syncthreads();

#pragma unroll
    for (int ks = 0; ks < 2; ++ks) {
      const int col = ks * 32 + lq * 8;
      s8v ah[2], al[2], bh[2], bl[2];
#pragma unroll
      for (int i = 0; i < 2; ++i) {
        ah[i] = *(const s8v*)&xh_s[(th * 32 + i * 16 + lm) * 72 + col];
        al[i] = *(const s8v*)&xl_s[(th * 32 + i * 16 + lm) * 72 + col];
        bh[i] = *(const s8v*)&wh_s[(kh * 32 + i * 16 + lm) * 72 + col];
        bl[i] = *(const s8v*)&wl_s[(kh * 32 + i * 16 + lm) * 72 + col];
      }
#pragma unroll
      for (int i = 0; i < 2; ++i)
#pragma unroll
        for (int j = 0; j < 2; ++j) {
          acc[i][j] = MFMA16(ah[i], bh[j], acc[i][j]);
          acc[i][j] = MFMA16(ah[i], bl[j], acc[i][j]);
          acc[i][j] = MFMA16(al[i], bh[j], acc[i][j]);
        }
    }
  }
  __syncthreads();

  // logits + bias -> LDS Ls[64 t][68] fp32 ; Ls2 = a^T staging [64 k][68]
  float* Ls = (float*)sm;            // 17408 B
  float* Ls2 = (float*)(sm + 8704);  // 17408 B
  const float bias[2] = {b[kh * 32 + lm], b[kh * 32 + 16 + lm]};
#pragma unroll
  for (int i = 0; i < 2; ++i)
#pragma unroll
    for (int j = 0; j < 2; ++j)
#pragma unroll
      for (int r = 0; r < 4; ++r)
        Ls[(th * 32 + i * 16 + lq * 4 + r) * 68 + kh * 32 + j * 16 + lm] =
            acc[i][j][r] + bias[j];
  __syncthreads();

  // softmax: 4 threads per t-row, 16 k each, register + shfl
  {
    const int row = tid >> 2, q = tid & 3;
    float av[16];
#pragma unroll
    for (int u = 0; u < 4; ++u)
      *(float4*)&av[u * 4] = *(const float4*)&Ls[row * 68 + q * 16 + u * 4];
    float m = av[0];
#pragma unroll
    for (int i = 1; i < 16; ++i) m = fmaxf(m, av[i]);
    m = fmaxf(m, __shfl_xor(m, 1, 64));
    m = fmaxf(m, __shfl_xor(m, 2, 64));
    float sum = 0.f;
#pragma unroll
    for (int i = 0; i < 16; ++i) {
      av[i] = __expf(av[i] - m);
      sum += av[i];
    }
    sum += __shfl_xor(sum, 1, 64);
    sum += __shfl_xor(sum, 2, 64);
    const float inv = 1.f / sum;
    float ps[16];
#pragma unroll
    for (int i = 0; i < 16; ++i) {
      av[i] *= inv;
      ps[i] = av[i];
      Ls2[(q * 16 + i) * 68 + row] = av[i];  // transposed a^T [k][t]
    }
#pragma unroll
    for (int s = 4; s < 64; s <<= 1)
#pragma unroll
      for (int i = 0; i < 16; ++i) ps[i] += __shfl_xor(ps[i], s, 64);
    if (lane < 4) {
#pragma unroll
      for (int i = 0; i < 16; ++i) asum_l[w * 64 + q * 16 + i] = ps[i];
    }
  }
  __syncthreads();

  if (tid < 64) {
    asum_part[(n * 16 + tl) * 64 + tid] = asum_l[tid] + asum_l[64 + tid] +
                                          asum_l[128 + tid] + asum_l[192 + tid];
  }
#pragma unroll
  for (int r = 0; r < 4; ++r) {
    const int u = tid + r * 256, k = u >> 4, tg = u & 15;
    *(float4*)&aT[((long)n * K + k) * T + tl * 64 + tg * 4] =
        *(const float4*)&Ls2[k * 68 + tg * 4];
  }
}

// ---------------------------------------------------------------------------
// k_gemm2: vlad[n,k,c] = sum_t a[t,k]*x[t,c] - asum*cent, full T per block.
// Grid N*16 = 512 blocks (n, 32c chunk) -> 2 blocks/CU. 256 threads
// (4 waves; wave = 32k x 16c, acc[2]). Fused epilogue: centroid subtract,
// vlad write, ssq partials [n][16][64] (no atomics).
// ---------------------------------------------------------------------------
__global__ __launch_bounds__(256, 4) void k_gemm2(
    const float* __restrict__ x, const float* __restrict__ aT,
    const float* __restrict__ asum_part, const float* __restrict__ cent,
    float* __restrict__ vlad, float* __restrict__ ssq_part) {
  __shared__ __align__(16) unsigned short sm[(2 * 64 + 2 * 32) * 72];  // 27648 B
  __shared__ float asum_l[64];
  __shared__ float ssq_l[128];
  unsigned short* ah_s = sm;                // a^T hi [64 k][72]
  unsigned short* al_s = sm + 64 * 72;
  unsigned short* xh_s = sm + 2 * 64 * 72;  // x^T hi [32 c][72]
  unsigned short* xl_s = sm + 2 * 64 * 72 + 32 * 72;

  const int tid = threadIdx.x;
  const int w = tid >> 6, lane = tid & 63, lm = lane & 15, lq = lane >> 4;
  const int kh = w >> 1;  // 32k half
  const int ch = w & 1;   // 16c half
  const int n = blockIdx.x >> 4, cq = blockIdx.x & 15;
  const int c0 = cq * 32;

  if (tid < 64) {
    float s = 0.f;
#pragma unroll
    for (int tl = 0; tl < 16; ++tl) s += asum_part[(n * 16 + tl) * 64 + tid];
    asum_l[tid] = s;
  }

  f4v acc[2] = {};
  float4 pa[4], px[2];
  // preload tile 0
#pragma unroll
  for (int r = 0; r < 4; ++r) {
    const int u = tid + r * 256, k = u >> 4, tg = u & 15;
    pa[r] = *(const float4*)&aT[((long)n * K + k) * T + tg * 4];
  }
  {
    const int cg = tid & 7, tq = tid >> 3;  // tq in [0,32), 2 t each
#pragma unroll
    for (int i = 0; i < 2; ++i)
      px[i] = *(const float4*)&x[((long)n * T + tq * 2 + i) * C + c0 + cg * 4];
  }

  for (int t0 = 0; t0 < T; t0 += 64) {
    __syncthreads();
    // a^T: fp32 -> hi/lo
#pragma unroll
    for (int r = 0; r < 4; ++r) {
      const int u = tid + r * 256, k = u >> 4, tg = u & 15;
      const float e[4] = {pa[r].x, pa[r].y, pa[r].z, pa[r].w};
      s4v h, l;
#pragma unroll
      for (int i = 0; i < 4; ++i) {
        unsigned short hb = f2bh(e[i]);
        h[i] = (short)hb;
        l[i] = (short)f2bh(e[i] - bh2f(hb));
      }
      *(s4v*)&ah_s[k * 72 + tg * 4] = h;
      *(s4v*)&al_s[k * 72 + tg * 4] = l;
    }
    // x^T: fp32 -> hi/lo, 2-t packed transposed writes (32 c rows)
    {
      const int cg = tid & 7, tq = tid >> 3;
#pragma unroll
      for (int cc = 0; cc < 4; ++cc) {
        s2v h, l;
#pragma unroll
        for (int i = 0; i < 2; ++i) {
          const float e = ((const float*)&px[i])[cc];
          unsigned short hb = f2bh(e);
          h[i] = (short)hb;
          l[i] = (short)f2bh(e - bh2f(hb));
        }
        *(s2v*)&xh_s[(cg * 4 + cc) * 72 + tq * 2] = h;
        *(s2v*)&xl_s[(cg * 4 + cc) * 72 + tq * 2] = l;
      }
    }
    if (t0 + 64 < T) {  // prefetch next t-tile
#pragma unroll
      for (int r = 0; r < 4; ++r) {
        const int u = tid + r * 256, k = u >> 4, tg = u & 15;
        pa[r] = *(const float4*)&aT[((long)n * K + k) * T + t0 + 64 + tg * 4];
      }
      const int cg = tid & 7, tq = tid >> 3;
#pragma unroll
      for (int i = 0; i < 2; ++i)
        px[i] = *(const float4*)&x[((long)n * T + t0 + 64 + tq * 2 + i) * C +
                                   c0 + cg * 4];
    }
    __syncthreads();

#pragma unroll
    for (int ks = 0; ks < 2; ++ks) {
      const int col = ks * 32 + lq * 8;
      s8v ah[2], al[2];
#pragma unroll
      for (int i = 0; i < 2; ++i) {
        ah[i] = *(const s8v*)&ah_s[(kh * 32 + i * 16 + lm) * 72 + col];
        al[i] = *(const s8v*)&al_s[(kh * 32 + i * 16 + lm) * 72 + col];
      }
      const s8v bh = *(const s8v*)&xh_s[(ch * 16 + lm) * 72 + col];
      const s8v bl = *(const s8v*)&xl_s[(ch * 16 + lm) * 72 + col];
#pragma unroll
      for (int i = 0; i < 2; ++i) {
        acc[i] = MFMA16(ah[i], bh, acc[i]);
        acc[i] = MFMA16(ah[i], bl, acc[i]);
        acc[i] = MFMA16(al[i], bh, acc[i]);
      }
    }
  }

  // fused epilogue: subtract asum*cent, write vlad, ssq partials
  float ssqp[2][4];
#pragma unroll
  for (int i = 0; i < 2; ++i) {
#pragma unroll
    for (int r = 0; r < 4; ++r) {
      const int k = kh * 32 + i * 16 + lq * 4 + r;
      const float as = asum_l[k];
      const int c = c0 + ch * 16 + lm;
      const float v = acc[i][r] - as * cent[(long)k * C + c];
      vlad[((long)n * K + k) * C + c] = v;
      ssqp[i][r] = v * v;
    }
  }
#pragma unroll
  for (int i = 0; i < 2; ++i)
#pragma unroll
    for (int r = 0; r < 4; ++r) {
      float s = ssqp[i][r];
      s += __shfl_xor(s, 1, 64);
      s += __shfl_xor(s, 2, 64);
      s += __shfl_xor(s, 4, 64);
      s += __shfl_xor(s, 8, 64);
      ssqp[i][r] = s;
    }
  if (lm == 0) {
#pragma unroll
    for (int i = 0; i < 2; ++i)
#pragma unroll
      for (int r = 0; r < 4; ++r)
        ssq_l[(kh * 32 + i * 16 + lq * 4 + r) * 2 + ch] = ssqp[i][r];
  }
  __syncthreads();
  if (tid < 64)
    ssq_part[(n * 16 + cq) * 64 + tid] = ssq_l[tid * 2] + ssq_l[tid * 2 + 1];
}

// ---------------------------------------------------------------------------
// k_norm: out = vlad / (||vlad_k|| * ||intra-normed||). Grid N*16 x 256.
// ---------------------------------------------------------------------------
__global__ __launch_bounds__(256) void k_norm(
    const float* __restrict__ vlad, const float* __restrict__ ssq_part,
    float* __restrict__ out) {
  __shared__ float denom[64];
  __shared__ float contrib[64];
  __shared__ float ginv;

  const int tid = threadIdx.x;
  const int n = blockIdx.x >> 4;
  const int chunk = blockIdx.x & 15;

  if (tid < 64) {
    float ss = 0.f;
#pragma unroll
    for (int q = 0; q < 16; ++q) ss += ssq_part[(n * 16 + q) * 64 + tid];
    const float d = fmaxf(sqrtf(ss), EPS);
    denom[tid] = d;
    contrib[tid] = ss / (d * d);
  }
  __syncthreads();
  if (tid == 0) {
    float s = 0.f;
#pragma unroll
    for (int k = 0; k < K; ++k) s += contrib[k];
    ginv = 1.0f / fmaxf(sqrtf(s), EPS);
  }
  __syncthreads();

#pragma unroll
  for (int q = 0; q < 2; ++q) {
    const int f4 = tid + q * 256;
    const long off = chunk * 2048 + (long)f4 * 4;
    const int k = (int)(off >> 9);
    float4 v = *(const float4*)&vlad[(long)n * K * C + off];
    const float sc = ginv / denom[k];
    v.x *= sc; v.y *= sc; v.z *= sc; v.w *= sc;
    *(float4*)&out[(long)n * K * C + off] = v;
  }
}

}  // namespace

extern "C" void kernel_launch(void* const* d_in, const int* in_sizes, int n_in,
                              void* d_out, int out_size, void* d_ws,
                              size_t ws_size, hipStream_t stream) {
  const float* x = reinterpret_cast<const float*>(d_in[0]);     // [N,T,C]
  const float* W = reinterpret_cast<const float*>(d_in[1]);     // [K,C]
  const float* b = reinterpret_cast<const float*>(d_in[2]);     // [K]
  const float* cent = reinterpret_cast<const float*>(d_in[3]);  // [K,C]
  float* out = reinterpret_cast<float*>(d_out);                 // [N, K*C]

  float* p = reinterpret_cast<float*>(d_ws);
  float* aTg = p;                 p += (size_t)N * K * T;   // 8 MiB
  float* vlad = p;                p += (size_t)N * K * C;   // 4 MiB
  float* asum_part = p;           p += (size_t)512 * 64;    // 128 KiB
  float* ssq_part = p;            // 128 KiB

  k_gemm1<<<(N * T) / 64, 256, 0, stream>>>(x, W, b, aTg, asum_part);
  k_gemm2<<<N * 16, 256, 0, stream>>>(x, aTg, asum_part, cent, vlad, ssq_part);
  k_norm<<<N * 16, 256, 0, stream>>>(vlad, ssq_part, out);
}